// Round 5
// baseline (155.893 us; speedup 1.0000x reference)
//
#include <hip/hip_runtime.h>

#define NXC 65536
#define TT 32
#define HH 128
#define TABN 6145                // lerp base entries over [-1, 2], delta = 2^-11
#define TABNP 6146               // stored values (one extra for last slope)
#define TABLO (-1.0f)
#define TABINV 2048.0f
#define OWNB 128                 // owned cells per block
#define WINB 256                 // block window cells (256 threads x 1)
#define HALOB 64                 // supports 16-step (64-stage) chunks exactly

typedef __attribute__((ext_vector_type(8))) short bf16x8;
typedef __attribute__((ext_vector_type(4))) float f32x4;
typedef unsigned short u16;

__device__ __forceinline__ float bf2f(u16 b) {
    union { unsigned int u; float f; } v; v.u = ((unsigned int)b) << 16; return v.f;
}
__device__ __forceinline__ u16 f2bf(float f) {
    union { float f; unsigned int u; } v; v.f = f;
    return (u16)((v.u + 0x7fffu + ((v.u >> 16) & 1u)) >> 16);  // RNE
}
__device__ __forceinline__ bool is_bf16_mode(const void* t) {
    return ((const u16*)t)[1] != 0;  // f32: hi half of t[0]=0.0f; bf16: t[1]=0x3C24
}

#if __has_builtin(__builtin_amdgcn_exp2f)
#define EXP2F(x) __builtin_amdgcn_exp2f(x)
#else
#define EXP2F(x) exp2f(x)
#endif
#if __has_builtin(__builtin_amdgcn_rcpf)
#define RCPF(x) __builtin_amdgcn_rcpf(x)
#else
#define RCPF(x) (1.0f / (x))
#endif

__device__ __forceinline__ float fast_tanh(float x) {
    float e = EXP2F(x * 2.8853900817779268f);
    return 1.0f - 2.0f * RCPF(e + 1.0f);
}

// Tabulate a(u) on grid u_e = TABLO + e/TABINV via the MFMA MLP.
// W2 B-fragments gathered directly from global W2 with the verified
// swizzle addressing (w2swz fused away); values bit-identical.
__global__ __launch_bounds__(256) void tabbuild_kernel(
    const void* traw, const void* W1, const void* W2, const void* W3,
    float* __restrict__ atab) {
    __shared__ float w1s[HH];
    __shared__ float w3s[HH];
    bool bf = is_bf16_mode(traw);
    int tid = threadIdx.x;
    if (tid < HH)
        w1s[tid] = bf ? bf2f(((const u16*)W1)[tid]) : ((const float*)W1)[tid];
    else
        w3s[tid - HH] = bf ? bf2f(((const u16*)W3)[tid - HH])
                           : ((const float*)W3)[tid - HH];
    __syncthreads();

    int lane = tid & 63;
    int wave = tid >> 6;
    int q = lane >> 4;
    int m = lane & 15;
    int base = (blockIdx.x * 4 + wave) * 16;
    float uin = TABLO + (float)(base + m) * (1.0f / TABINV);

    bf16x8 afrag[4];
#pragma unroll
    for (int ks = 0; ks < 4; ++ks)
#pragma unroll
        for (int j = 0; j < 8; ++j) {
            float h = fast_tanh(uin * w1s[ks * 32 + q * 8 + j]);
            afrag[ks][j] = (short)f2bf(h);
        }

    const u16* w2u = (const u16*)W2;
    const float* w2ff = (const float*)W2;
    float p0 = 0.f, p1 = 0.f, p2 = 0.f, p3 = 0.f;
#pragma unroll
    for (int nt = 0; nt < 8; ++nt) {
        f32x4 acc = {0.f, 0.f, 0.f, 0.f};
#pragma unroll
        for (int ks = 0; ks < 4; ++ks) {
            // B-fragment elems j: W2[ks*32 + q*8 + j][nt*16 + m]
            int idx0 = (ks * 32 + q * 8) * HH + nt * 16 + m;
            bf16x8 b;
#pragma unroll
            for (int j = 0; j < 8; ++j)
                b[j] = bf ? (short)w2u[idx0 + j * HH]
                          : (short)f2bf(w2ff[idx0 + j * HH]);
            acc = __builtin_amdgcn_mfma_f32_16x16x32_bf16(afrag[ks], b, acc, 0, 0, 0);
        }
        float w3v = w3s[nt * 16 + m];
        p0 += fast_tanh(acc[0]) * w3v;
        p1 += fast_tanh(acc[1]) * w3v;
        p2 += fast_tanh(acc[2]) * w3v;
        p3 += fast_tanh(acc[3]) * w3v;
    }
#pragma unroll
    for (int sh = 1; sh < 16; sh <<= 1) {
        p0 += __shfl_xor(p0, sh, 64);
        p1 += __shfl_xor(p1, sh, 64);
        p2 += __shfl_xor(p2, sh, 64);
        p3 += __shfl_xor(p3, sh, 64);
    }
    int r = m & 3;
    float a = (r == 0) ? p0 : (r == 1) ? p1 : (r == 2) ? p2 : p3;
    if (m < 4) {
        int e = base + q * 4 + r;
        if (e < TABNP) atab[e] = a;
    }
}

// One time-chunk (<=16 RK4 steps). Block owns OWNB=128 cells; its 256-cell
// window (halo 64/64) lives in registers, 1 cell/thread. 512 blocks =
// 2 independent blocks/CU for latency hiding. Cross-wave neighbor
// exchange: 2 edge values/wave/stage via parity-double-buffered LDS +
// ONE __syncthreads per stage (write p, barrier, read p; stage sigma+2's
// rewrite of p is gated behind barrier sigma+1 which follows all stage-
// sigma reads). a(u) via float2 (value,slope) LDS table: one ds_read_b64
// per lookup. Mask-free halo updates (bounded garbage reaches only
// [0,sigma-1] and [W-sigma, W-1]; owned [64,192) safe for sigma<=64);
// domain-boundary BCs are frozen ghost cells. s0==0 converts raw u0 and
// passes it through as output row 0.
__global__ __launch_bounds__(256) void chunk_kernel(
    const void* traw, const void* uin, float* __restrict__ uout,
    const void* Draw, const void* BCraw, const float* __restrict__ atab,
    void* __restrict__ outbase, int s0, int nsteps) {
    __shared__ __align__(16) float2 tab[TABN];
    __shared__ float t32s[TT];
    __shared__ float eL[2][4];
    __shared__ float eR[2][4];

    int tid = threadIdx.x;
    bool bf = is_bf16_mode(traw);

    // (value, slope) table: float4 loads, float4 LDS stores
    for (int e = tid * 4; e < TABN - 1; e += 1024) {
        float4 qv = *(const float4*)(atab + e);
        float nx = atab[e + 4];
        float4 lo = make_float4(qv.x, qv.y - qv.x, qv.y, qv.z - qv.y);
        float4 hi = make_float4(qv.z, qv.w - qv.z, qv.w, nx - qv.w);
        *(float4*)(&tab[e]) = lo;
        *(float4*)(&tab[e + 2]) = hi;
    }
    if (tid == 0)
        tab[TABN - 1] = make_float2(atab[TABN - 1], atab[TABN] - atab[TABN - 1]);
    if (tid < TT)
        t32s[tid] = bf ? bf2f(((const u16*)traw)[tid]) : ((const float*)traw)[tid];

    float d   = bf ? bf2f(((const u16*)Draw)[0])  : ((const float*)Draw)[0];
    float bc0 = bf ? bf2f(((const u16*)BCraw)[0]) : ((const float*)BCraw)[0];
    float bc1 = bf ? bf2f(((const u16*)BCraw)[1]) : ((const float*)BCraw)[1];

    int lane = tid & 63;
    int w = tid >> 6;                               // wave in block [0,4)
    int g = blockIdx.x * OWNB - HALOB + tid;        // this thread's cell
    bool gok = (g >= 0) && (g < NXC);
    bool own = (tid >= HALOB) && (tid < HALOB + OWNB);
    bool first = (s0 == 0);

    float v, ub;
    {
        float x;
        if (first) {
            if (bf) {
                u16 raw = gok ? ((const u16*)uin)[g] : (u16)0;
                x = bf2f(raw);
                if (own) ((u16*)outbase)[g] = raw;       // row 0 passthrough
            } else {
                float raw = gok ? ((const float*)uin)[g] : 0.f;
                x = raw;
                if (own) ((float*)outbase)[g] = raw;
            }
        } else {
            x = gok ? ((const float*)uin)[g] : 0.f;
        }
        if (!gok) x = (g < 0) ? bc0 : bc1;   // frozen ghost BC cells
        v = x;
        ub = x;
    }
    __syncthreads();  // table + t32s ready

    for (int st = 0; st < nsteps; ++st) {
        int step = s0 + st;
        float dt = t32s[step + 1] - t32s[step];
        float dt2 = 0.5f * dt, dt6 = dt * (1.0f / 6.0f);
        float kacc = 0.f;
#pragma unroll
        for (int s = 0; s < 4; ++s) {
            int p = s & 1;                      // stage parity (4 stages/step)
            float cnext = (s < 2) ? dt2 : dt;
            float wgt = (s == 1 || s == 2) ? 2.f : 1.f;
            if (lane == 63) eR[p][w] = v;       // wave's rightmost cell
            if (lane == 0)  eL[p][w] = v;       // wave's leftmost cell
            __syncthreads();
            float vl = __shfl_up(v, 1, 64);
            float vr = __shfl_down(v, 1, 64);
            if (lane == 0)  vl = (w > 0) ? eR[p][w - 1] : v;   // block edge:
            if (lane == 63) vr = (w < 3) ? eL[p][w + 1] : v;   // halo garbage ok
            float f = fmaf(v, TABINV, (-TABLO) * TABINV);
            f = fminf(fmaxf(f, 0.0f), (float)(TABN - 1));
            int e0 = (int)f;
            float frac = f - (float)e0;
            float2 ts = tab[e0];                // ds_read_b64
            float a = fmaf(frac, ts.y, ts.x);
            float ap = fmaxf(a, 0.f);
            float am = fminf(a, 0.f);
            float kv = (vl - v) * (d + ap) + (vr - v) * (d - am);
            kacc += wgt * kv;
            float nv = (s < 3) ? fmaf(cnext, kv, ub) : fmaf(dt6, kacc, ub);
            if (gok) {
                v = nv;
                if (s == 3) ub = nv;
            }
        }
        if (own) {
            size_t rb = (size_t)(step + 1) * NXC + g;
            if (bf) ((u16*)outbase)[rb] = f2bf(ub);
            else    ((float*)outbase)[rb] = ub;
        }
    }
    // chunk-final state for owned cells (skipped for the last chunk)
    if (uout != nullptr && own) uout[g] = ub;
}

extern "C" void kernel_launch(void* const* d_in, const int* in_sizes, int n_in,
                              void* d_out, int out_size, void* d_ws,
                              size_t ws_size, hipStream_t stream) {
    const void* t  = d_in[0];
    const void* u0 = d_in[1];
    const void* W1 = d_in[2];
    const void* W2 = d_in[3];
    const void* W3 = d_in[4];
    const void* Dp = d_in[5];
    const void* BC = d_in[6];

    float* atab = (float*)d_ws;                    // TABNP+2 floats
    float* uB = atab + TABNP + 2;                  // NXC f32 mid-state

    tabbuild_kernel<<<(TABNP + 63) / 64, 256, 0, stream>>>(t, W1, W2, W3, atab);

    chunk_kernel<<<NXC / OWNB, 256, 0, stream>>>(t, u0, uB, Dp, BC, atab,
                                                 d_out, 0, 16);
    chunk_kernel<<<NXC / OWNB, 256, 0, stream>>>(t, uB, nullptr, Dp, BC, atab,
                                                 d_out, 16, 15);
}

// Round 6
// 121.291 us; speedup vs baseline: 1.2853x; 1.2853x over previous
//
#include <hip/hip_runtime.h>

#define NXC 65536
#define TT 32
#define HH 128
#define TABN 6145                // lerp base entries over [-1, 2], delta = 2^-11
#define TABNP 6146               // stored values (one extra for last slope)
#define TABLO (-1.0f)
#define TABINV 2048.0f
#define THRB 320                 // threads per block (5 waves)
#define OUTB 64                  // owned cells per block
#define HALOB 128                // >= 124 stages: full single-launch integration
#define NSTEPS 31

typedef __attribute__((ext_vector_type(8))) short bf16x8;
typedef __attribute__((ext_vector_type(4))) float f32x4;
typedef unsigned short u16;

__device__ __forceinline__ float bf2f(u16 b) {
    union { unsigned int u; float f; } v; v.u = ((unsigned int)b) << 16; return v.f;
}
__device__ __forceinline__ u16 f2bf(float f) {
    union { float f; unsigned int u; } v; v.f = f;
    return (u16)((v.u + 0x7fffu + ((v.u >> 16) & 1u)) >> 16);  // RNE
}
__device__ __forceinline__ bool is_bf16_mode(const void* t) {
    return ((const u16*)t)[1] != 0;  // f32: hi half of t[0]=0.0f; bf16: t[1]=0x3C24
}

#if __has_builtin(__builtin_amdgcn_exp2f)
#define EXP2F(x) __builtin_amdgcn_exp2f(x)
#else
#define EXP2F(x) exp2f(x)
#endif
#if __has_builtin(__builtin_amdgcn_rcpf)
#define RCPF(x) __builtin_amdgcn_rcpf(x)
#else
#define RCPF(x) (1.0f / (x))
#endif

__device__ __forceinline__ float fast_tanh(float x) {
    float e = EXP2F(x * 2.8853900817779268f);
    return 1.0f - 2.0f * RCPF(e + 1.0f);
}

// W2[k][n] -> MFMA B-fragment order (bf16). Verified round-0 kernel.
__global__ void w2swz_kernel(const void* t, const void* W2,
                             u16* __restrict__ w2frag) {
    bool bf = is_bf16_mode(t);
    int i = blockIdx.x * 256 + threadIdx.x;  // [0, 16384)
    int j = i & 7;
    int lane = (i >> 3) & 63;
    int ks = (i >> 9) & 3;
    int nt = i >> 11;
    int k = ks * 32 + (lane >> 4) * 8 + j;
    int n = nt * 16 + (lane & 15);
    w2frag[i] = bf ? ((const u16*)W2)[k * HH + n]
                   : f2bf(((const float*)W2)[k * HH + n]);
}

// Tabulate a(u) on grid u_e = TABLO + e/TABINV via the MFMA MLP.
// Verified round-0 kernel (fragments read from global w2frag, coalesced).
__global__ __launch_bounds__(256) void tabbuild_kernel(
    const void* traw, const void* W1, const void* W3,
    const u16* __restrict__ w2frag, float* __restrict__ atab) {
    __shared__ float w1s[HH];
    __shared__ float w3s[HH];
    bool bf = is_bf16_mode(traw);
    int tid = threadIdx.x;
    if (tid < HH)
        w1s[tid] = bf ? bf2f(((const u16*)W1)[tid]) : ((const float*)W1)[tid];
    else
        w3s[tid - HH] = bf ? bf2f(((const u16*)W3)[tid - HH])
                           : ((const float*)W3)[tid - HH];
    __syncthreads();

    int lane = tid & 63;
    int wave = tid >> 6;
    int q = lane >> 4;
    int m = lane & 15;
    int base = (blockIdx.x * 4 + wave) * 16;
    float uin = TABLO + (float)(base + m) * (1.0f / TABINV);

    bf16x8 afrag[4];
#pragma unroll
    for (int ks = 0; ks < 4; ++ks)
#pragma unroll
        for (int j = 0; j < 8; ++j) {
            float h = fast_tanh(uin * w1s[ks * 32 + q * 8 + j]);
            afrag[ks][j] = (short)f2bf(h);
        }

    const bf16x8* w2f = (const bf16x8*)w2frag;   // global, coalesced 1KB/wave
    float p0 = 0.f, p1 = 0.f, p2 = 0.f, p3 = 0.f;
#pragma unroll
    for (int nt = 0; nt < 8; ++nt) {
        f32x4 acc = {0.f, 0.f, 0.f, 0.f};
#pragma unroll
        for (int ks = 0; ks < 4; ++ks) {
            bf16x8 b = w2f[(nt * 4 + ks) * 64 + lane];
            acc = __builtin_amdgcn_mfma_f32_16x16x32_bf16(afrag[ks], b, acc, 0, 0, 0);
        }
        float w3v = w3s[nt * 16 + m];
        p0 += fast_tanh(acc[0]) * w3v;
        p1 += fast_tanh(acc[1]) * w3v;
        p2 += fast_tanh(acc[2]) * w3v;
        p3 += fast_tanh(acc[3]) * w3v;
    }
#pragma unroll
    for (int sh = 1; sh < 16; sh <<= 1) {
        p0 += __shfl_xor(p0, sh, 64);
        p1 += __shfl_xor(p1, sh, 64);
        p2 += __shfl_xor(p2, sh, 64);
        p3 += __shfl_xor(p3, sh, 64);
    }
    int r = m & 3;
    float a = (r == 0) ? p0 : (r == 1) ? p1 : (r == 2) ? p2 : p3;
    if (m < 4) {
        int e = base + q * 4 + r;
        if (e < TABNP) atab[e] = a;
    }
}

// Single-launch full integration. Block = 320 threads (5 waves) owning
// OUTB=64 cells; 320-cell window (halo 128/128 >= 124 stages) in registers,
// 1 cell/thread. 1024 blocks = 4 independent blocks/CU (20 waves/CU) for
// latency hiding; LDS 24.8KB/block -> 99KB/CU. Cross-wave neighbor
// exchange: 2 edge values/wave/stage via parity-double-buffered LDS + ONE
// __syncthreads per stage (write p, barrier, read p; stage sigma+2's
// rewrite of p is gated behind barrier sigma+1 which follows all stage-
// sigma reads). a(u) via f32 LDS value table, slope in-chain (verified
// bit-identical). Mask-free halo updates (bounded garbage reaches only
// dist<=sigma from window edge; owned cells at dist>=128>124); domain-
// boundary BCs are frozen ghost cells. Row 0 = raw u0 passthrough.
__global__ __launch_bounds__(THRB) void integrate_kernel(
    const void* traw, const void* u0, const void* Draw, const void* BCraw,
    const float* __restrict__ atab, void* __restrict__ outbase) {
    __shared__ __align__(16) float tabs[TABNP + 2];
    __shared__ float t32s[TT];
    __shared__ float eL[2][5];
    __shared__ float eR[2][5];

    int tid = threadIdx.x;
    bool bf = is_bf16_mode(traw);

    // stage f32 value table: float4 copies across 320 threads
    for (int e = tid * 4; e < TABNP + 2; e += THRB * 4)
        *(float4*)(tabs + e) = *(const float4*)(atab + e);
    if (tid < TT)
        t32s[tid] = bf ? bf2f(((const u16*)traw)[tid]) : ((const float*)traw)[tid];

    float d   = bf ? bf2f(((const u16*)Draw)[0])  : ((const float*)Draw)[0];
    float bc0 = bf ? bf2f(((const u16*)BCraw)[0]) : ((const float*)BCraw)[0];
    float bc1 = bf ? bf2f(((const u16*)BCraw)[1]) : ((const float*)BCraw)[1];

    int lane = tid & 63;
    int w = tid >> 6;                               // wave in block [0,5)
    int g = blockIdx.x * OUTB - HALOB + tid;        // this thread's cell
    bool gok = (g >= 0) && (g < NXC);
    bool own = (tid >= HALOB) && (tid < HALOB + OUTB);

    float v, ub;
    {
        float x;
        if (bf) {
            u16 raw = gok ? ((const u16*)u0)[g] : (u16)0;
            x = bf2f(raw);
            if (own) ((u16*)outbase)[g] = raw;       // row 0 passthrough
        } else {
            float raw = gok ? ((const float*)u0)[g] : 0.f;
            x = raw;
            if (own) ((float*)outbase)[g] = raw;
        }
        if (!gok) x = (g < 0) ? bc0 : bc1;   // frozen ghost BC cells
        v = x;
        ub = x;
    }
    __syncthreads();  // table + t32s ready

    for (int st = 0; st < NSTEPS; ++st) {
        float dt = t32s[st + 1] - t32s[st];
        float dt2 = 0.5f * dt, dt6 = dt * (1.0f / 6.0f);
        float kacc = 0.f;
#pragma unroll
        for (int s = 0; s < 4; ++s) {
            int p = s & 1;                      // stage parity (4 stages/step)
            float cnext = (s < 2) ? dt2 : dt;
            float wgt = (s == 1 || s == 2) ? 2.f : 1.f;
            if (lane == 63) eR[p][w] = v;       // wave's rightmost cell
            if (lane == 0)  eL[p][w] = v;       // wave's leftmost cell
            __syncthreads();
            float vl = __shfl_up(v, 1, 64);
            float vr = __shfl_down(v, 1, 64);
            if (lane == 0)  vl = (w > 0) ? eR[p][w - 1] : v;   // block edge:
            if (lane == 63) vr = (w < 4) ? eL[p][w + 1] : v;   // halo garbage ok
            float f = fmaf(v, TABINV, (-TABLO) * TABINV);
            f = fminf(fmaxf(f, 0.0f), (float)(TABN - 1));
            int e0 = (int)f;
            float frac = f - (float)e0;
            float t0 = tabs[e0];
            float t1 = tabs[e0 + 1];
            float a = fmaf(frac, t1 - t0, t0);
            float ap = fmaxf(a, 0.f);
            float am = fminf(a, 0.f);
            float kv = (vl - v) * (d + ap) + (vr - v) * (d - am);
            kacc += wgt * kv;
            float nv = (s < 3) ? fmaf(cnext, kv, ub) : fmaf(dt6, kacc, ub);
            if (gok) {
                v = nv;
                if (s == 3) ub = nv;
            }
        }
        if (own) {
            size_t rb = (size_t)(st + 1) * NXC + g;
            if (bf) ((u16*)outbase)[rb] = f2bf(ub);
            else    ((float*)outbase)[rb] = ub;
        }
    }
}

extern "C" void kernel_launch(void* const* d_in, const int* in_sizes, int n_in,
                              void* d_out, int out_size, void* d_ws,
                              size_t ws_size, hipStream_t stream) {
    const void* t  = d_in[0];
    const void* u0 = d_in[1];
    const void* W1 = d_in[2];
    const void* W2 = d_in[3];
    const void* W3 = d_in[4];
    const void* Dp = d_in[5];
    const void* BC = d_in[6];

    float* atab = (float*)d_ws;                    // TABNP+2 floats
    u16* w2frag = (u16*)(atab + TABNP + 2);        // offset 24592 B, 16B-aligned

    w2swz_kernel<<<64, 256, 0, stream>>>(t, W2, w2frag);
    tabbuild_kernel<<<(TABNP + 63) / 64, 256, 0, stream>>>(t, W1, W3, w2frag, atab);
    integrate_kernel<<<NXC / OUTB, THRB, 0, stream>>>(t, u0, Dp, BC, atab, d_out);
}

// Round 7
// 108.694 us; speedup vs baseline: 1.4342x; 1.1159x over previous
//
#include <hip/hip_runtime.h>

#define NXC 65536
#define TT 32
#define HH 128
#define TABN 6145                // lerp base entries over [-1, 2], delta = 2^-11
#define TABNP 6146               // stored values (one extra for last slope)
#define TABLO (-1.0f)
#define TABINV 2048.0f
#define OUTW 32                  // output cells per wave
#define VC 3                     // window cells per lane
#define WINW 192                 // VC * 64
#define HALO 80                  // (WINW - OUTW) / 2; supports 20-step chunks

typedef __attribute__((ext_vector_type(8))) short bf16x8;
typedef __attribute__((ext_vector_type(4))) float f32x4;
typedef unsigned short u16;

__device__ __forceinline__ float bf2f(u16 b) {
    union { unsigned int u; float f; } v; v.u = ((unsigned int)b) << 16; return v.f;
}
__device__ __forceinline__ u16 f2bf(float f) {
    union { float f; unsigned int u; } v; v.f = f;
    return (u16)((v.u + 0x7fffu + ((v.u >> 16) & 1u)) >> 16);  // RNE
}
__device__ __forceinline__ bool is_bf16_mode(const void* t) {
    return ((const u16*)t)[1] != 0;  // f32: hi half of t[0]=0.0f; bf16: t[1]=0x3C24
}

#if __has_builtin(__builtin_amdgcn_exp2f)
#define EXP2F(x) __builtin_amdgcn_exp2f(x)
#else
#define EXP2F(x) exp2f(x)
#endif
#if __has_builtin(__builtin_amdgcn_rcpf)
#define RCPF(x) __builtin_amdgcn_rcpf(x)
#else
#define RCPF(x) (1.0f / (x))
#endif

__device__ __forceinline__ float fast_tanh(float x) {
    float e = EXP2F(x * 2.8853900817779268f);
    return 1.0f - 2.0f * RCPF(e + 1.0f);
}

// W2[k][n] -> MFMA B-fragment order (bf16). Verified round-0 kernel.
__global__ void w2swz_kernel(const void* t, const void* W2,
                             u16* __restrict__ w2frag) {
    bool bf = is_bf16_mode(t);
    int i = blockIdx.x * 256 + threadIdx.x;  // [0, 16384)
    int j = i & 7;
    int lane = (i >> 3) & 63;
    int ks = (i >> 9) & 3;
    int nt = i >> 11;
    int k = ks * 32 + (lane >> 4) * 8 + j;
    int n = nt * 16 + (lane & 15);
    w2frag[i] = bf ? ((const u16*)W2)[k * HH + n]
                   : f2bf(((const float*)W2)[k * HH + n]);
}

// Tabulate a(u) on grid u_e = TABLO + e/TABINV via the MFMA MLP.
// Verified round-0 kernel (fragments read from global w2frag, coalesced).
__global__ __launch_bounds__(256) void tabbuild_kernel(
    const void* traw, const void* W1, const void* W3,
    const u16* __restrict__ w2frag, float* __restrict__ atab) {
    __shared__ float w1s[HH];
    __shared__ float w3s[HH];
    bool bf = is_bf16_mode(traw);
    int tid = threadIdx.x;
    if (tid < HH)
        w1s[tid] = bf ? bf2f(((const u16*)W1)[tid]) : ((const float*)W1)[tid];
    else
        w3s[tid - HH] = bf ? bf2f(((const u16*)W3)[tid - HH])
                           : ((const float*)W3)[tid - HH];
    __syncthreads();

    int lane = tid & 63;
    int wave = tid >> 6;
    int q = lane >> 4;
    int m = lane & 15;
    int base = (blockIdx.x * 4 + wave) * 16;
    float uin = TABLO + (float)(base + m) * (1.0f / TABINV);

    bf16x8 afrag[4];
#pragma unroll
    for (int ks = 0; ks < 4; ++ks)
#pragma unroll
        for (int j = 0; j < 8; ++j) {
            float h = fast_tanh(uin * w1s[ks * 32 + q * 8 + j]);
            afrag[ks][j] = (short)f2bf(h);
        }

    const bf16x8* w2f = (const bf16x8*)w2frag;   // global, coalesced 1KB/wave
    float p0 = 0.f, p1 = 0.f, p2 = 0.f, p3 = 0.f;
#pragma unroll
    for (int nt = 0; nt < 8; ++nt) {
        f32x4 acc = {0.f, 0.f, 0.f, 0.f};
#pragma unroll
        for (int ks = 0; ks < 4; ++ks) {
            bf16x8 b = w2f[(nt * 4 + ks) * 64 + lane];
            acc = __builtin_amdgcn_mfma_f32_16x16x32_bf16(afrag[ks], b, acc, 0, 0, 0);
        }
        float w3v = w3s[nt * 16 + m];
        p0 += fast_tanh(acc[0]) * w3v;
        p1 += fast_tanh(acc[1]) * w3v;
        p2 += fast_tanh(acc[2]) * w3v;
        p3 += fast_tanh(acc[3]) * w3v;
    }
#pragma unroll
    for (int sh = 1; sh < 16; sh <<= 1) {
        p0 += __shfl_xor(p0, sh, 64);
        p1 += __shfl_xor(p1, sh, 64);
        p2 += __shfl_xor(p2, sh, 64);
        p3 += __shfl_xor(p3, sh, 64);
    }
    int r = m & 3;
    float a = (r == 0) ? p0 : (r == 1) ? p1 : (r == 2) ? p2 : p3;
    if (m < 4) {
        int e = base + q * 4 + r;
        if (e < TABNP) atab[e] = a;
    }
}

// One time-chunk (<=16 RK4 steps used). Wave owns OUTW=32 cells; its
// 192-cell window (halo 80/80) lives in registers, VC=3 cells/lane.
// 512 blocks = 2 independent blocks/CU (2 waves/SIMD) -> one wave's
// exposed gather chain hides under the other's issue. Barrier-free main
// loop; neighbor exchange = 2 shuffles/stage; a(u) via f32 LDS value
// table, ds_read2_b32 pair, slope in-chain (bit-identical to the
// verified round-3 kernel). Mask-free stages: halo cells update with
// wrong-but-bounded data (never reaches owned cells: owned at window-
// local [80,112), garbage reaches dist<=sigma<=64 from edges; table
// index clamped). Domain-boundary BCs are frozen ghost cells. s0==0
// converts raw u0 and passes it through as output row 0.
__global__ __launch_bounds__(256) void chunk_kernel(
    const void* traw, const void* uin, float* __restrict__ uout,
    const void* Draw, const void* BCraw, const float* __restrict__ atab,
    void* __restrict__ outbase, int s0, int nsteps) {
    __shared__ __align__(16) float tabs[TABNP + 2];
    __shared__ float t32s[TT];

    int tid = threadIdx.x;
    bool bf = is_bf16_mode(traw);

    // stage f32 value table: 1537 float4 copies across 256 threads
    for (int e = tid * 4; e < TABNP + 2; e += 1024)
        *(float4*)(tabs + e) = *(const float4*)(atab + e);
    if (tid < TT)
        t32s[tid] = bf ? bf2f(((const u16*)traw)[tid]) : ((const float*)traw)[tid];

    float d   = bf ? bf2f(((const u16*)Draw)[0])  : ((const float*)Draw)[0];
    float bc0 = bf ? bf2f(((const u16*)BCraw)[0]) : ((const float*)BCraw)[0];
    float bc1 = bf ? bf2f(((const u16*)BCraw)[1]) : ((const float*)BCraw)[1];

    int lane = tid & 63;
    int wid = blockIdx.x * 4 + (tid >> 6);
    int gb = wid * OUTW - HALO + lane * VC;   // this lane's first cell (global)
    int i0 = lane * VC;                        // window-local
    bool first = (s0 == 0);

    float v[VC], ub[VC];
    bool gok[VC], own[VC];
#pragma unroll
    for (int j = 0; j < VC; ++j) {
        int g = gb + j;
        int i = i0 + j;
        gok[j] = (g >= 0) && (g < NXC);
        own[j] = (i >= HALO) && (i < HALO + OUTW);
        float x;
        if (first) {
            if (bf) {
                u16 raw = gok[j] ? ((const u16*)uin)[g] : (u16)0;
                x = bf2f(raw);
                if (own[j]) ((u16*)outbase)[g] = raw;       // row 0 passthrough
            } else {
                float raw = gok[j] ? ((const float*)uin)[g] : 0.f;
                x = raw;
                if (own[j]) ((float*)outbase)[g] = raw;
            }
        } else {
            x = gok[j] ? ((const float*)uin)[g] : 0.f;
        }
        if (!gok[j]) x = (g < 0) ? bc0 : bc1;   // frozen ghost BC cells
        v[j] = x;
        ub[j] = x;
    }
    __syncthreads();  // table + t32s ready; no barriers after this

    for (int st = 0; st < nsteps; ++st) {
        int step = s0 + st;
        float dt = t32s[step + 1] - t32s[step];
        float dt2 = 0.5f * dt, dt6 = dt * (1.0f / 6.0f);
        float kacc[VC], kv[VC];
#pragma unroll
        for (int j = 0; j < VC; ++j) kacc[j] = 0.f;
#pragma unroll
        for (int s = 0; s < 4; ++s) {
            float cnext = (s < 2) ? dt2 : dt;
            float wgt = (s == 1 || s == 2) ? 2.f : 1.f;
            float vup = __shfl_up(v[VC - 1], 1, 64);   // left nbr of cell j=0
            float vdn = __shfl_down(v[0], 1, 64);      // right nbr of j=VC-1
#pragma unroll
            for (int j = 0; j < VC; ++j) {
                float vc = v[j];
                float vl = (j == 0) ? vup : v[j - 1];
                float vr = (j == VC - 1) ? vdn : v[j + 1];
                float f = fmaf(vc, TABINV, (-TABLO) * TABINV);
                f = fminf(fmaxf(f, 0.0f), (float)(TABN - 1));
                int e0 = (int)f;
                float frac = f - (float)e0;
                float t0 = tabs[e0];           // ds_read2_b32 pair
                float t1 = tabs[e0 + 1];
                float a = fmaf(frac, t1 - t0, t0);
                float ap = fmaxf(a, 0.f);
                float am = fminf(a, 0.f);
                kv[j] = (vl - vc) * (d + ap) + (vr - vc) * (d - am);
            }
#pragma unroll
            for (int j = 0; j < VC; ++j) {
                kacc[j] += wgt * kv[j];
                float nv = (s < 3) ? fmaf(cnext, kv[j], ub[j])
                                   : fmaf(dt6, kacc[j], ub[j]);
                if (gok[j]) {
                    v[j] = nv;
                    if (s == 3) ub[j] = nv;
                }
            }
        }
        if (bf) {
            u16* orow = (u16*)outbase + (size_t)(step + 1) * NXC;
#pragma unroll
            for (int j = 0; j < VC; ++j)
                if (own[j]) orow[gb + j] = f2bf(ub[j]);
        } else {
            float* orow = (float*)outbase + (size_t)(step + 1) * NXC;
#pragma unroll
            for (int j = 0; j < VC; ++j)
                if (own[j]) orow[gb + j] = ub[j];
        }
    }
    // chunk-final state for owned cells (skipped for the last chunk)
    if (uout != nullptr) {
#pragma unroll
        for (int j = 0; j < VC; ++j)
            if (own[j]) uout[gb + j] = ub[j];
    }
}

extern "C" void kernel_launch(void* const* d_in, const int* in_sizes, int n_in,
                              void* d_out, int out_size, void* d_ws,
                              size_t ws_size, hipStream_t stream) {
    const void* t  = d_in[0];
    const void* u0 = d_in[1];
    const void* W1 = d_in[2];
    const void* W2 = d_in[3];
    const void* W3 = d_in[4];
    const void* Dp = d_in[5];
    const void* BC = d_in[6];

    float* atab = (float*)d_ws;                    // TABNP+2 floats
    u16* w2frag = (u16*)(atab + TABNP + 2);        // offset 24592 B, 16B-aligned
    float* uB = (float*)(w2frag + 16384);          // NXC f32 mid-state

    w2swz_kernel<<<64, 256, 0, stream>>>(t, W2, w2frag);
    tabbuild_kernel<<<(TABNP + 63) / 64, 256, 0, stream>>>(t, W1, W3, w2frag, atab);

    const int grid = NXC / (OUTW * 4);             // 512 blocks
    chunk_kernel<<<grid, 256, 0, stream>>>(t, u0, uB, Dp, BC, atab, d_out, 0, 16);
    chunk_kernel<<<grid, 256, 0, stream>>>(t, uB, nullptr, Dp, BC, atab, d_out, 16, 15);
}

// Round 8
// 108.612 us; speedup vs baseline: 1.4353x; 1.0008x over previous
//
#include <hip/hip_runtime.h>

#define NXC 65536
#define TT 32
#define HH 128
#define TABN 6145                // lerp base entries over [-1, 2], delta = 2^-11
#define TABNP 6146               // stored values (one extra for last slope)
#define TABLO (-1.0f)
#define TABINV 2048.0f
#define OUTW 32                  // output cells per wave
#define VC 3                     // window cells per lane
#define WINW 192                 // VC * 64
#define HALO 80                  // (WINW - OUTW) / 2; supports 20-step chunks

typedef __attribute__((ext_vector_type(8))) short bf16x8;
typedef __attribute__((ext_vector_type(4))) float f32x4;
typedef unsigned short u16;

__device__ __forceinline__ float bf2f(u16 b) {
    union { unsigned int u; float f; } v; v.u = ((unsigned int)b) << 16; return v.f;
}
__device__ __forceinline__ u16 f2bf(float f) {
    union { float f; unsigned int u; } v; v.f = f;
    return (u16)((v.u + 0x7fffu + ((v.u >> 16) & 1u)) >> 16);  // RNE
}
__device__ __forceinline__ bool is_bf16_mode(const void* t) {
    return ((const u16*)t)[1] != 0;  // f32: hi half of t[0]=0.0f; bf16: t[1]=0x3C24
}

#if __has_builtin(__builtin_amdgcn_exp2f)
#define EXP2F(x) __builtin_amdgcn_exp2f(x)
#else
#define EXP2F(x) exp2f(x)
#endif
#if __has_builtin(__builtin_amdgcn_rcpf)
#define RCPF(x) __builtin_amdgcn_rcpf(x)
#else
#define RCPF(x) (1.0f / (x))
#endif

__device__ __forceinline__ float fast_tanh(float x) {
    float e = EXP2F(x * 2.8853900817779268f);
    return 1.0f - 2.0f * RCPF(e + 1.0f);
}

// Whole-wave lane shifts via DPP (VALU, ~8cy, no LDS pipe), replacing
// ds_permute-based __shfl_up/__shfl_down on the stage critical chain.
// wave_shr:1 (0x138): lane i <- lane i-1 (== __shfl_up(x,1));  lane 0
// keeps src (bound_ctrl=false, old=src) == __shfl_up edge behavior.
// wave_shl:1 (0x130): lane i <- lane i+1 (== __shfl_down(x,1)); lane 63
// keeps src. Bit-identical to the verified shuffle version everywhere.
__device__ __forceinline__ float dpp_up1(float x) {
    int xi = __float_as_int(x);
    int r = __builtin_amdgcn_update_dpp(xi, xi, 0x138, 0xf, 0xf, false);
    return __int_as_float(r);
}
__device__ __forceinline__ float dpp_dn1(float x) {
    int xi = __float_as_int(x);
    int r = __builtin_amdgcn_update_dpp(xi, xi, 0x130, 0xf, 0xf, false);
    return __int_as_float(r);
}

// W2[k][n] -> MFMA B-fragment order (bf16). Verified round-0 kernel.
__global__ void w2swz_kernel(const void* t, const void* W2,
                             u16* __restrict__ w2frag) {
    bool bf = is_bf16_mode(t);
    int i = blockIdx.x * 256 + threadIdx.x;  // [0, 16384)
    int j = i & 7;
    int lane = (i >> 3) & 63;
    int ks = (i >> 9) & 3;
    int nt = i >> 11;
    int k = ks * 32 + (lane >> 4) * 8 + j;
    int n = nt * 16 + (lane & 15);
    w2frag[i] = bf ? ((const u16*)W2)[k * HH + n]
                   : f2bf(((const float*)W2)[k * HH + n]);
}

// Tabulate a(u) on grid u_e = TABLO + e/TABINV via the MFMA MLP.
// Verified round-0 kernel (fragments read from global w2frag, coalesced).
__global__ __launch_bounds__(256) void tabbuild_kernel(
    const void* traw, const void* W1, const void* W3,
    const u16* __restrict__ w2frag, float* __restrict__ atab) {
    __shared__ float w1s[HH];
    __shared__ float w3s[HH];
    bool bf = is_bf16_mode(traw);
    int tid = threadIdx.x;
    if (tid < HH)
        w1s[tid] = bf ? bf2f(((const u16*)W1)[tid]) : ((const float*)W1)[tid];
    else
        w3s[tid - HH] = bf ? bf2f(((const u16*)W3)[tid - HH])
                           : ((const float*)W3)[tid - HH];
    __syncthreads();

    int lane = tid & 63;
    int wave = tid >> 6;
    int q = lane >> 4;
    int m = lane & 15;
    int base = (blockIdx.x * 4 + wave) * 16;
    float uin = TABLO + (float)(base + m) * (1.0f / TABINV);

    bf16x8 afrag[4];
#pragma unroll
    for (int ks = 0; ks < 4; ++ks)
#pragma unroll
        for (int j = 0; j < 8; ++j) {
            float h = fast_tanh(uin * w1s[ks * 32 + q * 8 + j]);
            afrag[ks][j] = (short)f2bf(h);
        }

    const bf16x8* w2f = (const bf16x8*)w2frag;   // global, coalesced 1KB/wave
    float p0 = 0.f, p1 = 0.f, p2 = 0.f, p3 = 0.f;
#pragma unroll
    for (int nt = 0; nt < 8; ++nt) {
        f32x4 acc = {0.f, 0.f, 0.f, 0.f};
#pragma unroll
        for (int ks = 0; ks < 4; ++ks) {
            bf16x8 b = w2f[(nt * 4 + ks) * 64 + lane];
            acc = __builtin_amdgcn_mfma_f32_16x16x32_bf16(afrag[ks], b, acc, 0, 0, 0);
        }
        float w3v = w3s[nt * 16 + m];
        p0 += fast_tanh(acc[0]) * w3v;
        p1 += fast_tanh(acc[1]) * w3v;
        p2 += fast_tanh(acc[2]) * w3v;
        p3 += fast_tanh(acc[3]) * w3v;
    }
#pragma unroll
    for (int sh = 1; sh < 16; sh <<= 1) {
        p0 += __shfl_xor(p0, sh, 64);
        p1 += __shfl_xor(p1, sh, 64);
        p2 += __shfl_xor(p2, sh, 64);
        p3 += __shfl_xor(p3, sh, 64);
    }
    int r = m & 3;
    float a = (r == 0) ? p0 : (r == 1) ? p1 : (r == 2) ? p2 : p3;
    if (m < 4) {
        int e = base + q * 4 + r;
        if (e < TABNP) atab[e] = a;
    }
}

// One time-chunk (<=16 RK4 steps used). Wave owns OUTW=32 cells; its
// 192-cell window (halo 80/80) lives in registers, VC=3 cells/lane.
// 512 blocks = 2 independent blocks/CU (2 waves/SIMD). Barrier-free main
// loop; neighbor exchange = 2 DPP wave-shifts/stage (VALU, off the LDS
// pipe and ~15x lower latency than ds_permute shuffles); a(u) via f32
// LDS value table, ds_read2_b32 pair, slope in-chain (bit-identical to
// the verified round-3 kernel). Mask-free stages: halo cells update with
// wrong-but-bounded data (never reaches owned cells: owned at window-
// local [80,112), garbage reaches dist<=sigma<=64 from edges; table
// index clamped). Domain-boundary BCs are frozen ghost cells. s0==0
// converts raw u0 and passes it through as output row 0.
__global__ __launch_bounds__(256) void chunk_kernel(
    const void* traw, const void* uin, float* __restrict__ uout,
    const void* Draw, const void* BCraw, const float* __restrict__ atab,
    void* __restrict__ outbase, int s0, int nsteps) {
    __shared__ __align__(16) float tabs[TABNP + 2];
    __shared__ float t32s[TT];

    int tid = threadIdx.x;
    bool bf = is_bf16_mode(traw);

    // stage f32 value table: 1537 float4 copies across 256 threads
    for (int e = tid * 4; e < TABNP + 2; e += 1024)
        *(float4*)(tabs + e) = *(const float4*)(atab + e);
    if (tid < TT)
        t32s[tid] = bf ? bf2f(((const u16*)traw)[tid]) : ((const float*)traw)[tid];

    float d   = bf ? bf2f(((const u16*)Draw)[0])  : ((const float*)Draw)[0];
    float bc0 = bf ? bf2f(((const u16*)BCraw)[0]) : ((const float*)BCraw)[0];
    float bc1 = bf ? bf2f(((const u16*)BCraw)[1]) : ((const float*)BCraw)[1];

    int lane = tid & 63;
    int wid = blockIdx.x * 4 + (tid >> 6);
    int gb = wid * OUTW - HALO + lane * VC;   // this lane's first cell (global)
    int i0 = lane * VC;                        // window-local
    bool first = (s0 == 0);

    float v[VC], ub[VC];
    bool gok[VC], own[VC];
#pragma unroll
    for (int j = 0; j < VC; ++j) {
        int g = gb + j;
        int i = i0 + j;
        gok[j] = (g >= 0) && (g < NXC);
        own[j] = (i >= HALO) && (i < HALO + OUTW);
        float x;
        if (first) {
            if (bf) {
                u16 raw = gok[j] ? ((const u16*)uin)[g] : (u16)0;
                x = bf2f(raw);
                if (own[j]) ((u16*)outbase)[g] = raw;       // row 0 passthrough
            } else {
                float raw = gok[j] ? ((const float*)uin)[g] : 0.f;
                x = raw;
                if (own[j]) ((float*)outbase)[g] = raw;
            }
        } else {
            x = gok[j] ? ((const float*)uin)[g] : 0.f;
        }
        if (!gok[j]) x = (g < 0) ? bc0 : bc1;   // frozen ghost BC cells
        v[j] = x;
        ub[j] = x;
    }
    __syncthreads();  // table + t32s ready; no barriers after this

    for (int st = 0; st < nsteps; ++st) {
        int step = s0 + st;
        float dt = t32s[step + 1] - t32s[step];
        float dt2 = 0.5f * dt, dt6 = dt * (1.0f / 6.0f);
        float kacc[VC], kv[VC];
#pragma unroll
        for (int j = 0; j < VC; ++j) kacc[j] = 0.f;
#pragma unroll
        for (int s = 0; s < 4; ++s) {
            float cnext = (s < 2) ? dt2 : dt;
            float wgt = (s == 1 || s == 2) ? 2.f : 1.f;
            float vup = dpp_up1(v[VC - 1]);    // left nbr of cell j=0
            float vdn = dpp_dn1(v[0]);         // right nbr of j=VC-1
#pragma unroll
            for (int j = 0; j < VC; ++j) {
                float vc = v[j];
                float vl = (j == 0) ? vup : v[j - 1];
                float vr = (j == VC - 1) ? vdn : v[j + 1];
                float f = fmaf(vc, TABINV, (-TABLO) * TABINV);
                f = fminf(fmaxf(f, 0.0f), (float)(TABN - 1));
                int e0 = (int)f;
                float frac = f - (float)e0;
                float t0 = tabs[e0];           // ds_read2_b32 pair
                float t1 = tabs[e0 + 1];
                float a = fmaf(frac, t1 - t0, t0);
                float ap = fmaxf(a, 0.f);
                float am = fminf(a, 0.f);
                kv[j] = (vl - vc) * (d + ap) + (vr - vc) * (d - am);
            }
#pragma unroll
            for (int j = 0; j < VC; ++j) {
                kacc[j] += wgt * kv[j];
                float nv = (s < 3) ? fmaf(cnext, kv[j], ub[j])
                                   : fmaf(dt6, kacc[j], ub[j]);
                if (gok[j]) {
                    v[j] = nv;
                    if (s == 3) ub[j] = nv;
                }
            }
        }
        if (bf) {
            u16* orow = (u16*)outbase + (size_t)(step + 1) * NXC;
#pragma unroll
            for (int j = 0; j < VC; ++j)
                if (own[j]) orow[gb + j] = f2bf(ub[j]);
        } else {
            float* orow = (float*)outbase + (size_t)(step + 1) * NXC;
#pragma unroll
            for (int j = 0; j < VC; ++j)
                if (own[j]) orow[gb + j] = ub[j];
        }
    }
    // chunk-final state for owned cells (skipped for the last chunk)
    if (uout != nullptr) {
#pragma unroll
        for (int j = 0; j < VC; ++j)
            if (own[j]) uout[gb + j] = ub[j];
    }
}

extern "C" void kernel_launch(void* const* d_in, const int* in_sizes, int n_in,
                              void* d_out, int out_size, void* d_ws,
                              size_t ws_size, hipStream_t stream) {
    const void* t  = d_in[0];
    const void* u0 = d_in[1];
    const void* W1 = d_in[2];
    const void* W2 = d_in[3];
    const void* W3 = d_in[4];
    const void* Dp = d_in[5];
    const void* BC = d_in[6];

    float* atab = (float*)d_ws;                    // TABNP+2 floats
    u16* w2frag = (u16*)(atab + TABNP + 2);        // offset 24592 B, 16B-aligned
    float* uB = (float*)(w2frag + 16384);          // NXC f32 mid-state

    w2swz_kernel<<<64, 256, 0, stream>>>(t, W2, w2frag);
    tabbuild_kernel<<<(TABNP + 63) / 64, 256, 0, stream>>>(t, W1, W3, w2frag, atab);

    const int grid = NXC / (OUTW * 4);             // 512 blocks
    chunk_kernel<<<grid, 256, 0, stream>>>(t, u0, uB, Dp, BC, atab, d_out, 0, 16);
    chunk_kernel<<<grid, 256, 0, stream>>>(t, uB, nullptr, Dp, BC, atab, d_out, 16, 15);
}

// Round 9
// 100.455 us; speedup vs baseline: 1.5519x; 1.0812x over previous
//
#include <hip/hip_runtime.h>

#define NXC 65536
#define TT 32
#define HH 128
#define TABN 6145                // lerp base entries over [-1, 2], delta = 2^-11
#define TABNP 6146               // stored values (one extra for last slope)
#define TABLO (-1.0f)
#define TABINV 2048.0f
#define OUTW 64                  // output cells per wave
#define VC 3                     // window cells per lane
#define WINW 192                 // VC * 64
#define HALO 64                  // (WINW - OUTW) / 2; supports 16-step chunks

typedef __attribute__((ext_vector_type(8))) short bf16x8;
typedef __attribute__((ext_vector_type(4))) float f32x4;
typedef unsigned short u16;

__device__ __forceinline__ float bf2f(u16 b) {
    union { unsigned int u; float f; } v; v.u = ((unsigned int)b) << 16; return v.f;
}
__device__ __forceinline__ u16 f2bf(float f) {
    union { float f; unsigned int u; } v; v.f = f;
    return (u16)((v.u + 0x7fffu + ((v.u >> 16) & 1u)) >> 16);  // RNE
}
__device__ __forceinline__ bool is_bf16_mode(const void* t) {
    return ((const u16*)t)[1] != 0;  // f32: hi half of t[0]=0.0f; bf16: t[1]=0x3C24
}

#if __has_builtin(__builtin_amdgcn_exp2f)
#define EXP2F(x) __builtin_amdgcn_exp2f(x)
#else
#define EXP2F(x) exp2f(x)
#endif
#if __has_builtin(__builtin_amdgcn_rcpf)
#define RCPF(x) __builtin_amdgcn_rcpf(x)
#else
#define RCPF(x) (1.0f / (x))
#endif

__device__ __forceinline__ float fast_tanh(float x) {
    float e = EXP2F(x * 2.8853900817779268f);
    return 1.0f - 2.0f * RCPF(e + 1.0f);
}

// Whole-wave lane shifts via DPP (VALU, ~8cy, off the LDS pipe), replacing
// ds_permute-based __shfl_up/__shfl_down on the stage critical chain.
// wave_shr:1 (0x138): lane i <- lane i-1 (== __shfl_up(x,1)); lane 0 keeps
// src (bound_ctrl=false, old=src) == __shfl_up edge behavior.
// wave_shl:1 (0x130): lane i <- lane i+1 (== __shfl_down(x,1)); lane 63
// keeps src. HW-verified bit-identical to the shuffle version in round 8
// (absmax unchanged). At 1 wave/SIMD (this round's config) the removed
// ~120cy ds_permute latency is fully exposed -> direct per-stage saving.
__device__ __forceinline__ float dpp_up1(float x) {
    int xi = __float_as_int(x);
    int r = __builtin_amdgcn_update_dpp(xi, xi, 0x138, 0xf, 0xf, false);
    return __int_as_float(r);
}
__device__ __forceinline__ float dpp_dn1(float x) {
    int xi = __float_as_int(x);
    int r = __builtin_amdgcn_update_dpp(xi, xi, 0x130, 0xf, 0xf, false);
    return __int_as_float(r);
}

// W2[k][n] -> MFMA B-fragment order (bf16). Verified round-0 kernel.
__global__ void w2swz_kernel(const void* t, const void* W2,
                             u16* __restrict__ w2frag) {
    bool bf = is_bf16_mode(t);
    int i = blockIdx.x * 256 + threadIdx.x;  // [0, 16384)
    int j = i & 7;
    int lane = (i >> 3) & 63;
    int ks = (i >> 9) & 3;
    int nt = i >> 11;
    int k = ks * 32 + (lane >> 4) * 8 + j;
    int n = nt * 16 + (lane & 15);
    w2frag[i] = bf ? ((const u16*)W2)[k * HH + n]
                   : f2bf(((const float*)W2)[k * HH + n]);
}

// Tabulate a(u) on grid u_e = TABLO + e/TABINV via the MFMA MLP.
// Verified round-0 kernel (fragments read from global w2frag, coalesced).
__global__ __launch_bounds__(256) void tabbuild_kernel(
    const void* traw, const void* W1, const void* W3,
    const u16* __restrict__ w2frag, float* __restrict__ atab) {
    __shared__ float w1s[HH];
    __shared__ float w3s[HH];
    bool bf = is_bf16_mode(traw);
    int tid = threadIdx.x;
    if (tid < HH)
        w1s[tid] = bf ? bf2f(((const u16*)W1)[tid]) : ((const float*)W1)[tid];
    else
        w3s[tid - HH] = bf ? bf2f(((const u16*)W3)[tid - HH])
                           : ((const float*)W3)[tid - HH];
    __syncthreads();

    int lane = tid & 63;
    int wave = tid >> 6;
    int q = lane >> 4;
    int m = lane & 15;
    int base = (blockIdx.x * 4 + wave) * 16;
    float uin = TABLO + (float)(base + m) * (1.0f / TABINV);

    bf16x8 afrag[4];
#pragma unroll
    for (int ks = 0; ks < 4; ++ks)
#pragma unroll
        for (int j = 0; j < 8; ++j) {
            float h = fast_tanh(uin * w1s[ks * 32 + q * 8 + j]);
            afrag[ks][j] = (short)f2bf(h);
        }

    const bf16x8* w2f = (const bf16x8*)w2frag;   // global, coalesced 1KB/wave
    float p0 = 0.f, p1 = 0.f, p2 = 0.f, p3 = 0.f;
#pragma unroll
    for (int nt = 0; nt < 8; ++nt) {
        f32x4 acc = {0.f, 0.f, 0.f, 0.f};
#pragma unroll
        for (int ks = 0; ks < 4; ++ks) {
            bf16x8 b = w2f[(nt * 4 + ks) * 64 + lane];
            acc = __builtin_amdgcn_mfma_f32_16x16x32_bf16(afrag[ks], b, acc, 0, 0, 0);
        }
        float w3v = w3s[nt * 16 + m];
        p0 += fast_tanh(acc[0]) * w3v;
        p1 += fast_tanh(acc[1]) * w3v;
        p2 += fast_tanh(acc[2]) * w3v;
        p3 += fast_tanh(acc[3]) * w3v;
    }
#pragma unroll
    for (int sh = 1; sh < 16; sh <<= 1) {
        p0 += __shfl_xor(p0, sh, 64);
        p1 += __shfl_xor(p1, sh, 64);
        p2 += __shfl_xor(p2, sh, 64);
        p3 += __shfl_xor(p3, sh, 64);
    }
    int r = m & 3;
    float a = (r == 0) ? p0 : (r == 1) ? p1 : (r == 2) ? p2 : p3;
    if (m < 4) {
        int e = base + q * 4 + r;
        if (e < TABNP) atab[e] = a;
    }
}

// One time-chunk (<=16 RK4 steps). Wave owns OUTW=64 cells; its 192-cell
// window (halo 64/64) lives in registers, VC=3 cells/lane. 256 blocks =
// 1 block/CU, 4 waves/CU (1 wave/SIMD), barrier-free main loop — the
// round-3 verified structure (session-best e2e), with the round-8
// HW-verified DPP lane shifts replacing the ds_permute shuffles on the
// fully-exposed per-stage chain. a(u) via f32 LDS value table,
// ds_read2_b32 pair, slope in-chain (bit-identical). Mask-free stages:
// halo cells update with wrong-but-bounded data (never reaches owned
// cells: dist >= 64 >= stages; table index clamped). Domain-boundary BCs
// are frozen ghost cells. s0==0 converts raw u0 and passes it through as
// output row 0.
__global__ __launch_bounds__(256) void chunk_kernel(
    const void* traw, const void* uin, float* __restrict__ uout,
    const void* Draw, const void* BCraw, const float* __restrict__ atab,
    void* __restrict__ outbase, int s0, int nsteps) {
    __shared__ __align__(16) float tabs[TABNP + 2];
    __shared__ float t32s[TT];

    int tid = threadIdx.x;
    bool bf = is_bf16_mode(traw);

    // stage f32 value table: 1537 float4 copies across 256 threads
    for (int e = tid * 4; e < TABNP + 2; e += 1024)
        *(float4*)(tabs + e) = *(const float4*)(atab + e);
    if (tid < TT)
        t32s[tid] = bf ? bf2f(((const u16*)traw)[tid]) : ((const float*)traw)[tid];

    float d   = bf ? bf2f(((const u16*)Draw)[0])  : ((const float*)Draw)[0];
    float bc0 = bf ? bf2f(((const u16*)BCraw)[0]) : ((const float*)BCraw)[0];
    float bc1 = bf ? bf2f(((const u16*)BCraw)[1]) : ((const float*)BCraw)[1];

    int lane = tid & 63;
    int wid = blockIdx.x * 4 + (tid >> 6);
    int gb = wid * OUTW - HALO + lane * VC;   // this lane's first cell (global)
    int i0 = lane * VC;                        // window-local
    bool first = (s0 == 0);

    float v[VC], ub[VC];
    bool gok[VC], own[VC];
#pragma unroll
    for (int j = 0; j < VC; ++j) {
        int g = gb + j;
        int i = i0 + j;
        gok[j] = (g >= 0) && (g < NXC);
        own[j] = (i >= HALO) && (i < HALO + OUTW);
        float x;
        if (first) {
            if (bf) {
                u16 raw = gok[j] ? ((const u16*)uin)[g] : (u16)0;
                x = bf2f(raw);
                if (own[j]) ((u16*)outbase)[g] = raw;       // row 0 passthrough
            } else {
                float raw = gok[j] ? ((const float*)uin)[g] : 0.f;
                x = raw;
                if (own[j]) ((float*)outbase)[g] = raw;
            }
        } else {
            x = gok[j] ? ((const float*)uin)[g] : 0.f;
        }
        if (!gok[j]) x = (g < 0) ? bc0 : bc1;   // frozen ghost BC cells
        v[j] = x;
        ub[j] = x;
    }
    __syncthreads();  // table + t32s ready; no barriers after this

    for (int st = 0; st < nsteps; ++st) {
        int step = s0 + st;
        float dt = t32s[step + 1] - t32s[step];
        float dt2 = 0.5f * dt, dt6 = dt * (1.0f / 6.0f);
        float kacc[VC], kv[VC];
#pragma unroll
        for (int j = 0; j < VC; ++j) kacc[j] = 0.f;
#pragma unroll
        for (int s = 0; s < 4; ++s) {
            float cnext = (s < 2) ? dt2 : dt;
            float wgt = (s == 1 || s == 2) ? 2.f : 1.f;
            float vup = dpp_up1(v[VC - 1]);    // left nbr of cell j=0
            float vdn = dpp_dn1(v[0]);         // right nbr of j=VC-1
#pragma unroll
            for (int j = 0; j < VC; ++j) {
                float vc = v[j];
                float vl = (j == 0) ? vup : v[j - 1];
                float vr = (j == VC - 1) ? vdn : v[j + 1];
                float f = fmaf(vc, TABINV, (-TABLO) * TABINV);
                f = fminf(fmaxf(f, 0.0f), (float)(TABN - 1));
                int e0 = (int)f;
                float frac = f - (float)e0;
                float t0 = tabs[e0];           // ds_read2_b32 pair
                float t1 = tabs[e0 + 1];
                float a = fmaf(frac, t1 - t0, t0);
                float ap = fmaxf(a, 0.f);
                float am = fminf(a, 0.f);
                kv[j] = (vl - vc) * (d + ap) + (vr - vc) * (d - am);
            }
#pragma unroll
            for (int j = 0; j < VC; ++j) {
                kacc[j] += wgt * kv[j];
                float nv = (s < 3) ? fmaf(cnext, kv[j], ub[j])
                                   : fmaf(dt6, kacc[j], ub[j]);
                if (gok[j]) {
                    v[j] = nv;
                    if (s == 3) ub[j] = nv;
                }
            }
        }
        if (bf) {
            u16* orow = (u16*)outbase + (size_t)(step + 1) * NXC;
#pragma unroll
            for (int j = 0; j < VC; ++j)
                if (own[j]) orow[gb + j] = f2bf(ub[j]);
        } else {
            float* orow = (float*)outbase + (size_t)(step + 1) * NXC;
#pragma unroll
            for (int j = 0; j < VC; ++j)
                if (own[j]) orow[gb + j] = ub[j];
        }
    }
    // chunk-final state for owned cells (skipped for the last chunk)
    if (uout != nullptr) {
#pragma unroll
        for (int j = 0; j < VC; ++j)
            if (own[j]) uout[gb + j] = ub[j];
    }
}

extern "C" void kernel_launch(void* const* d_in, const int* in_sizes, int n_in,
                              void* d_out, int out_size, void* d_ws,
                              size_t ws_size, hipStream_t stream) {
    const void* t  = d_in[0];
    const void* u0 = d_in[1];
    const void* W1 = d_in[2];
    const void* W2 = d_in[3];
    const void* W3 = d_in[4];
    const void* Dp = d_in[5];
    const void* BC = d_in[6];

    float* atab = (float*)d_ws;                    // TABNP+2 floats
    u16* w2frag = (u16*)(atab + TABNP + 2);        // offset 24592 B, 16B-aligned
    float* uB = (float*)(w2frag + 16384);          // NXC f32 mid-state

    w2swz_kernel<<<64, 256, 0, stream>>>(t, W2, w2frag);
    tabbuild_kernel<<<(TABNP + 63) / 64, 256, 0, stream>>>(t, W1, W3, w2frag, atab);

    chunk_kernel<<<NXC / (OUTW * 4), 256, 0, stream>>>(t, u0, uB, Dp, BC, atab,
                                                       d_out, 0, 16);
    chunk_kernel<<<NXC / (OUTW * 4), 256, 0, stream>>>(t, uB, nullptr, Dp, BC, atab,
                                                       d_out, 16, 15);
}

// Round 10
// 100.141 us; speedup vs baseline: 1.5567x; 1.0031x over previous
//
#include <hip/hip_runtime.h>

#define NXC 65536
#define TT 32
#define HH 128
#define TABN 6145                // lerp base entries over [-1, 2], delta = 2^-11
#define TABNP 6146               // stored values (one extra for last slope)
#define TABLO (-1.0f)
#define TABINV 2048.0f
#define OUTW 64                  // output cells per wave
#define VC 3                     // window cells per lane
#define WINW 192                 // VC * 64
#define HALO 64                  // (WINW - OUTW) / 2; supports 16-step chunks

typedef __attribute__((ext_vector_type(8))) short bf16x8;
typedef __attribute__((ext_vector_type(4))) float f32x4;
typedef unsigned short u16;

__device__ __forceinline__ float bf2f(u16 b) {
    union { unsigned int u; float f; } v; v.u = ((unsigned int)b) << 16; return v.f;
}
__device__ __forceinline__ u16 f2bf(float f) {
    union { float f; unsigned int u; } v; v.f = f;
    return (u16)((v.u + 0x7fffu + ((v.u >> 16) & 1u)) >> 16);  // RNE
}
__device__ __forceinline__ bool is_bf16_mode(const void* t) {
    return ((const u16*)t)[1] != 0;  // f32: hi half of t[0]=0.0f; bf16: t[1]=0x3C24
}

#if __has_builtin(__builtin_amdgcn_exp2f)
#define EXP2F(x) __builtin_amdgcn_exp2f(x)
#else
#define EXP2F(x) exp2f(x)
#endif
#if __has_builtin(__builtin_amdgcn_rcpf)
#define RCPF(x) __builtin_amdgcn_rcpf(x)
#else
#define RCPF(x) (1.0f / (x))
#endif

__device__ __forceinline__ float fast_tanh(float x) {
    float e = EXP2F(x * 2.8853900817779268f);
    return 1.0f - 2.0f * RCPF(e + 1.0f);
}

// Whole-wave lane shifts via DPP (VALU, off the LDS pipe). HW-verified
// bit-identical to __shfl_up/__shfl_down(x,1) incl. edge lanes (R8/R9).
__device__ __forceinline__ float dpp_up1(float x) {
    int xi = __float_as_int(x);
    int r = __builtin_amdgcn_update_dpp(xi, xi, 0x138, 0xf, 0xf, false);
    return __int_as_float(r);
}
__device__ __forceinline__ float dpp_dn1(float x) {
    int xi = __float_as_int(x);
    int r = __builtin_amdgcn_update_dpp(xi, xi, 0x130, 0xf, 0xf, false);
    return __int_as_float(r);
}

// W2[k][n] -> MFMA B-fragment order (bf16). Verified round-0 kernel.
__global__ void w2swz_kernel(const void* t, const void* W2,
                             u16* __restrict__ w2frag) {
    bool bf = is_bf16_mode(t);
    int i = blockIdx.x * 256 + threadIdx.x;  // [0, 16384)
    int j = i & 7;
    int lane = (i >> 3) & 63;
    int ks = (i >> 9) & 3;
    int nt = i >> 11;
    int k = ks * 32 + (lane >> 4) * 8 + j;
    int n = nt * 16 + (lane & 15);
    w2frag[i] = bf ? ((const u16*)W2)[k * HH + n]
                   : f2bf(((const float*)W2)[k * HH + n]);
}

// Tabulate a(u) on grid u_e = TABLO + e/TABINV via the MFMA MLP.
// Verified round-0 kernel (fragments read from global w2frag, coalesced).
__global__ __launch_bounds__(256) void tabbuild_kernel(
    const void* traw, const void* W1, const void* W3,
    const u16* __restrict__ w2frag, float* __restrict__ atab) {
    __shared__ float w1s[HH];
    __shared__ float w3s[HH];
    bool bf = is_bf16_mode(traw);
    int tid = threadIdx.x;
    if (tid < HH)
        w1s[tid] = bf ? bf2f(((const u16*)W1)[tid]) : ((const float*)W1)[tid];
    else
        w3s[tid - HH] = bf ? bf2f(((const u16*)W3)[tid - HH])
                           : ((const float*)W3)[tid - HH];
    __syncthreads();

    int lane = tid & 63;
    int wave = tid >> 6;
    int q = lane >> 4;
    int m = lane & 15;
    int base = (blockIdx.x * 4 + wave) * 16;
    float uin = TABLO + (float)(base + m) * (1.0f / TABINV);

    bf16x8 afrag[4];
#pragma unroll
    for (int ks = 0; ks < 4; ++ks)
#pragma unroll
        for (int j = 0; j < 8; ++j) {
            float h = fast_tanh(uin * w1s[ks * 32 + q * 8 + j]);
            afrag[ks][j] = (short)f2bf(h);
        }

    const bf16x8* w2f = (const bf16x8*)w2frag;   // global, coalesced 1KB/wave
    float p0 = 0.f, p1 = 0.f, p2 = 0.f, p3 = 0.f;
#pragma unroll
    for (int nt = 0; nt < 8; ++nt) {
        f32x4 acc = {0.f, 0.f, 0.f, 0.f};
#pragma unroll
        for (int ks = 0; ks < 4; ++ks) {
            bf16x8 b = w2f[(nt * 4 + ks) * 64 + lane];
            acc = __builtin_amdgcn_mfma_f32_16x16x32_bf16(afrag[ks], b, acc, 0, 0, 0);
        }
        float w3v = w3s[nt * 16 + m];
        p0 += fast_tanh(acc[0]) * w3v;
        p1 += fast_tanh(acc[1]) * w3v;
        p2 += fast_tanh(acc[2]) * w3v;
        p3 += fast_tanh(acc[3]) * w3v;
    }
#pragma unroll
    for (int sh = 1; sh < 16; sh <<= 1) {
        p0 += __shfl_xor(p0, sh, 64);
        p1 += __shfl_xor(p1, sh, 64);
        p2 += __shfl_xor(p2, sh, 64);
        p3 += __shfl_xor(p3, sh, 64);
    }
    int r = m & 3;
    float a = (r == 0) ? p0 : (r == 1) ? p1 : (r == 2) ? p2 : p3;
    if (m < 4) {
        int e = base + q * 4 + r;
        if (e < TABNP) atab[e] = a;
    }
}

// One time-chunk (<=16 RK4 steps). Round-9 verified structure (wave owns
// OUTW=64 cells, 192-cell register window, halo 64/64, 1 block/CU,
// barrier-free, DPP lane shifts, f32 LDS value table) with the table
// gather SOFTWARE-PIPELINED ACROSS STAGES: the stage-(s+1) lookup for
// cell j depends only on cell j's own updated value, so its index calc +
// ds_read2 are issued immediately after v[j]'s update in stage s and
// consumed at the start of stage s+1 — hiding the ~120cy LDS latency
// under the remaining update VALU + DPP + early flux of the next stage.
// Pure reorder of bit-identical ops (table immutable after staging
// barrier; !gok cells re-issue from unchanged v). Mask-free stages /
// frozen ghost BCs / clamped index exactly as verified. s0==0 converts
// raw u0 and passes it through as output row 0.
__global__ __launch_bounds__(256) void chunk_kernel(
    const void* traw, const void* uin, float* __restrict__ uout,
    const void* Draw, const void* BCraw, const float* __restrict__ atab,
    void* __restrict__ outbase, int s0, int nsteps) {
    __shared__ __align__(16) float tabs[TABNP + 2];
    __shared__ float t32s[TT];

    int tid = threadIdx.x;
    bool bf = is_bf16_mode(traw);

    // stage f32 value table: 1537 float4 copies across 256 threads
    for (int e = tid * 4; e < TABNP + 2; e += 1024)
        *(float4*)(tabs + e) = *(const float4*)(atab + e);
    if (tid < TT)
        t32s[tid] = bf ? bf2f(((const u16*)traw)[tid]) : ((const float*)traw)[tid];

    float d   = bf ? bf2f(((const u16*)Draw)[0])  : ((const float*)Draw)[0];
    float bc0 = bf ? bf2f(((const u16*)BCraw)[0]) : ((const float*)BCraw)[0];
    float bc1 = bf ? bf2f(((const u16*)BCraw)[1]) : ((const float*)BCraw)[1];

    int lane = tid & 63;
    int wid = blockIdx.x * 4 + (tid >> 6);
    int gb = wid * OUTW - HALO + lane * VC;   // this lane's first cell (global)
    int i0 = lane * VC;                        // window-local
    bool first = (s0 == 0);

    float v[VC], ub[VC];
    bool gok[VC], own[VC];
#pragma unroll
    for (int j = 0; j < VC; ++j) {
        int g = gb + j;
        int i = i0 + j;
        gok[j] = (g >= 0) && (g < NXC);
        own[j] = (i >= HALO) && (i < HALO + OUTW);
        float x;
        if (first) {
            if (bf) {
                u16 raw = gok[j] ? ((const u16*)uin)[g] : (u16)0;
                x = bf2f(raw);
                if (own[j]) ((u16*)outbase)[g] = raw;       // row 0 passthrough
            } else {
                float raw = gok[j] ? ((const float*)uin)[g] : 0.f;
                x = raw;
                if (own[j]) ((float*)outbase)[g] = raw;
            }
        } else {
            x = gok[j] ? ((const float*)uin)[g] : 0.f;
        }
        if (!gok[j]) x = (g < 0) ? bc0 : bc1;   // frozen ghost BC cells
        v[j] = x;
        ub[j] = x;
    }
    __syncthreads();  // table + t32s ready; no barriers after this

    // pending table lookup per cell: frac + (t0, t1) issued from current v[j]
    float pf[VC], pt0[VC], pt1[VC];
#pragma unroll
    for (int j = 0; j < VC; ++j) {
        float f = fmaf(v[j], TABINV, (-TABLO) * TABINV);
        f = fminf(fmaxf(f, 0.0f), (float)(TABN - 1));
        int e0 = (int)f;
        pf[j] = f - (float)e0;
        pt0[j] = tabs[e0];                   // ds_read2_b32 pair, in flight
        pt1[j] = tabs[e0 + 1];
    }

    for (int st = 0; st < nsteps; ++st) {
        int step = s0 + st;
        float dt = t32s[step + 1] - t32s[step];
        float dt2 = 0.5f * dt, dt6 = dt * (1.0f / 6.0f);
        float kacc[VC], kv[VC];
#pragma unroll
        for (int j = 0; j < VC; ++j) kacc[j] = 0.f;
#pragma unroll
        for (int s = 0; s < 4; ++s) {
            float cnext = (s < 2) ? dt2 : dt;
            float wgt = (s == 1 || s == 2) ? 2.f : 1.f;
            float vup = dpp_up1(v[VC - 1]);    // left nbr of cell j=0
            float vdn = dpp_dn1(v[0]);         // right nbr of j=VC-1
#pragma unroll
            for (int j = 0; j < VC; ++j) {
                float vc = v[j];
                float vl = (j == 0) ? vup : v[j - 1];
                float vr = (j == VC - 1) ? vdn : v[j + 1];
                float a = fmaf(pf[j], pt1[j] - pt0[j], pt0[j]);  // consume
                float ap = fmaxf(a, 0.f);
                float am = fminf(a, 0.f);
                kv[j] = (vl - vc) * (d + ap) + (vr - vc) * (d - am);
            }
#pragma unroll
            for (int j = 0; j < VC; ++j) {
                kacc[j] += wgt * kv[j];
                float nv = (s < 3) ? fmaf(cnext, kv[j], ub[j])
                                   : fmaf(dt6, kacc[j], ub[j]);
                if (gok[j]) {
                    v[j] = nv;
                    if (s == 3) ub[j] = nv;
                }
                // issue next stage's lookup from the just-updated v[j]
                float f = fmaf(v[j], TABINV, (-TABLO) * TABINV);
                f = fminf(fmaxf(f, 0.0f), (float)(TABN - 1));
                int e0 = (int)f;
                pf[j] = f - (float)e0;
                pt0[j] = tabs[e0];
                pt1[j] = tabs[e0 + 1];
            }
        }
        if (bf) {
            u16* orow = (u16*)outbase + (size_t)(step + 1) * NXC;
#pragma unroll
            for (int j = 0; j < VC; ++j)
                if (own[j]) orow[gb + j] = f2bf(ub[j]);
        } else {
            float* orow = (float*)outbase + (size_t)(step + 1) * NXC;
#pragma unroll
            for (int j = 0; j < VC; ++j)
                if (own[j]) orow[gb + j] = ub[j];
        }
    }
    // chunk-final state for owned cells (skipped for the last chunk)
    if (uout != nullptr) {
#pragma unroll
        for (int j = 0; j < VC; ++j)
            if (own[j]) uout[gb + j] = ub[j];
    }
}

extern "C" void kernel_launch(void* const* d_in, const int* in_sizes, int n_in,
                              void* d_out, int out_size, void* d_ws,
                              size_t ws_size, hipStream_t stream) {
    const void* t  = d_in[0];
    const void* u0 = d_in[1];
    const void* W1 = d_in[2];
    const void* W2 = d_in[3];
    const void* W3 = d_in[4];
    const void* Dp = d_in[5];
    const void* BC = d_in[6];

    float* atab = (float*)d_ws;                    // TABNP+2 floats
    u16* w2frag = (u16*)(atab + TABNP + 2);        // offset 24592 B, 16B-aligned
    float* uB = (float*)(w2frag + 16384);          // NXC f32 mid-state

    w2swz_kernel<<<64, 256, 0, stream>>>(t, W2, w2frag);
    tabbuild_kernel<<<(TABNP + 63) / 64, 256, 0, stream>>>(t, W1, W3, w2frag, atab);

    chunk_kernel<<<NXC / (OUTW * 4), 256, 0, stream>>>(t, u0, uB, Dp, BC, atab,
                                                       d_out, 0, 16);
    chunk_kernel<<<NXC / (OUTW * 4), 256, 0, stream>>>(t, uB, nullptr, Dp, BC, atab,
                                                       d_out, 16, 15);
}

// Round 11
// 98.228 us; speedup vs baseline: 1.5870x; 1.0195x over previous
//
#include <hip/hip_runtime.h>

#define NXC 65536
#define TT 32
#define HH 128
#define TABN 6145                // lerp base entries over [-1, 2], delta = 2^-11
#define TABNP 6146               // stored values (one extra for last slope)
#define TABLO (-1.0f)
#define TABINV 2048.0f
#define OUTW 64                  // output cells per wave
#define VC 3                     // window cells per lane
#define WINW 192                 // VC * 64
#define HALO 64                  // (WINW - OUTW) / 2; supports 16-step chunks

typedef __attribute__((ext_vector_type(8))) short bf16x8;
typedef __attribute__((ext_vector_type(4))) float f32x4;
typedef unsigned short u16;

__device__ __forceinline__ float bf2f(u16 b) {
    union { unsigned int u; float f; } v; v.u = ((unsigned int)b) << 16; return v.f;
}
__device__ __forceinline__ u16 f2bf(float f) {
    union { float f; unsigned int u; } v; v.f = f;
    return (u16)((v.u + 0x7fffu + ((v.u >> 16) & 1u)) >> 16);  // RNE
}
__device__ __forceinline__ bool is_bf16_mode(const void* t) {
    return ((const u16*)t)[1] != 0;  // f32: hi half of t[0]=0.0f; bf16: t[1]=0x3C24
}

#if __has_builtin(__builtin_amdgcn_exp2f)
#define EXP2F(x) __builtin_amdgcn_exp2f(x)
#else
#define EXP2F(x) exp2f(x)
#endif
#if __has_builtin(__builtin_amdgcn_rcpf)
#define RCPF(x) __builtin_amdgcn_rcpf(x)
#else
#define RCPF(x) (1.0f / (x))
#endif
// fract(f) == f - (float)(int)f exactly for clamped f in [0, TABN-1]
#if __has_builtin(__builtin_amdgcn_fractf)
#define FRACTF(x) __builtin_amdgcn_fractf(x)
#else
#define FRACTF(x) ((x) - floorf(x))
#endif

__device__ __forceinline__ float fast_tanh(float x) {
    float e = EXP2F(x * 2.8853900817779268f);
    return 1.0f - 2.0f * RCPF(e + 1.0f);
}

// Whole-wave lane shifts via DPP (VALU, off the LDS pipe). HW-verified
// bit-identical to __shfl_up/__shfl_down(x,1) incl. edge lanes (R8/R9).
__device__ __forceinline__ float dpp_up1(float x) {
    int xi = __float_as_int(x);
    int r = __builtin_amdgcn_update_dpp(xi, xi, 0x138, 0xf, 0xf, false);
    return __int_as_float(r);
}
__device__ __forceinline__ float dpp_dn1(float x) {
    int xi = __float_as_int(x);
    int r = __builtin_amdgcn_update_dpp(xi, xi, 0x130, 0xf, 0xf, false);
    return __int_as_float(r);
}

// W2[k][n] -> MFMA B-fragment order (bf16). Verified round-0 kernel.
__global__ void w2swz_kernel(const void* t, const void* W2,
                             u16* __restrict__ w2frag) {
    bool bf = is_bf16_mode(t);
    int i = blockIdx.x * 256 + threadIdx.x;  // [0, 16384)
    int j = i & 7;
    int lane = (i >> 3) & 63;
    int ks = (i >> 9) & 3;
    int nt = i >> 11;
    int k = ks * 32 + (lane >> 4) * 8 + j;
    int n = nt * 16 + (lane & 15);
    w2frag[i] = bf ? ((const u16*)W2)[k * HH + n]
                   : f2bf(((const float*)W2)[k * HH + n]);
}

// Tabulate a(u) on grid u_e = TABLO + e/TABINV via the MFMA MLP.
// Verified round-0 kernel (fragments read from global w2frag, coalesced).
__global__ __launch_bounds__(256) void tabbuild_kernel(
    const void* traw, const void* W1, const void* W3,
    const u16* __restrict__ w2frag, float* __restrict__ atab) {
    __shared__ float w1s[HH];
    __shared__ float w3s[HH];
    bool bf = is_bf16_mode(traw);
    int tid = threadIdx.x;
    if (tid < HH)
        w1s[tid] = bf ? bf2f(((const u16*)W1)[tid]) : ((const float*)W1)[tid];
    else
        w3s[tid - HH] = bf ? bf2f(((const u16*)W3)[tid - HH])
                           : ((const float*)W3)[tid - HH];
    __syncthreads();

    int lane = tid & 63;
    int wave = tid >> 6;
    int q = lane >> 4;
    int m = lane & 15;
    int base = (blockIdx.x * 4 + wave) * 16;
    float uin = TABLO + (float)(base + m) * (1.0f / TABINV);

    bf16x8 afrag[4];
#pragma unroll
    for (int ks = 0; ks < 4; ++ks)
#pragma unroll
        for (int j = 0; j < 8; ++j) {
            float h = fast_tanh(uin * w1s[ks * 32 + q * 8 + j]);
            afrag[ks][j] = (short)f2bf(h);
        }

    const bf16x8* w2f = (const bf16x8*)w2frag;   // global, coalesced 1KB/wave
    float p0 = 0.f, p1 = 0.f, p2 = 0.f, p3 = 0.f;
#pragma unroll
    for (int nt = 0; nt < 8; ++nt) {
        f32x4 acc = {0.f, 0.f, 0.f, 0.f};
#pragma unroll
        for (int ks = 0; ks < 4; ++ks) {
            bf16x8 b = w2f[(nt * 4 + ks) * 64 + lane];
            acc = __builtin_amdgcn_mfma_f32_16x16x32_bf16(afrag[ks], b, acc, 0, 0, 0);
        }
        float w3v = w3s[nt * 16 + m];
        p0 += fast_tanh(acc[0]) * w3v;
        p1 += fast_tanh(acc[1]) * w3v;
        p2 += fast_tanh(acc[2]) * w3v;
        p3 += fast_tanh(acc[3]) * w3v;
    }
#pragma unroll
    for (int sh = 1; sh < 16; sh <<= 1) {
        p0 += __shfl_xor(p0, sh, 64);
        p1 += __shfl_xor(p1, sh, 64);
        p2 += __shfl_xor(p2, sh, 64);
        p3 += __shfl_xor(p3, sh, 64);
    }
    int r = m & 3;
    float a = (r == 0) ? p0 : (r == 1) ? p1 : (r == 2) ? p2 : p3;
    if (m < 4) {
        int e = base + q * 4 + r;
        if (e < TABNP) atab[e] = a;
    }
}

// One time-chunk (<=16 RK4 steps). Round-10 session-best structure (wave
// owns OUTW=64 cells, 192-cell register window, halo 64/64, 1 block/CU,
// barrier-free, DPP shifts, pipelined table lookups) with per-stage issue
// cuts, all bit-identical:
//  - unconditional v/ub update; frozen ghost-BC lanes repaired per stage
//    under a block-uniform branch taken ONLY by blocks 0 and 255 (the
//    only blocks with out-of-domain lanes) -> deletes 2 cndmask/cell
//    everywhere else. Ghost pending-lookup garbage only feeds the ghost
//    cell's own discarded flux, never owned cells.
//  - float2 (value,slope) table: slope subtraction done once at staging
//    (same subtraction of same values as the in-loop version; R2/R4-
//    verified), one ds_read_b64 per lookup.
//  - v_fract for frac (exact for clamped f >= 0).
// Mask-free halo updates / clamped index exactly as verified. s0==0
// converts raw u0 and passes it through as output row 0.
__global__ __launch_bounds__(256) void chunk_kernel(
    const void* traw, const void* uin, float* __restrict__ uout,
    const void* Draw, const void* BCraw, const float* __restrict__ atab,
    void* __restrict__ outbase, int s0, int nsteps) {
    __shared__ __align__(16) float2 tab[TABN];
    __shared__ float t32s[TT];

    int tid = threadIdx.x;
    bool bf = is_bf16_mode(traw);

    // (value, slope) table: float4 loads, float4 LDS stores (R4-verified)
    for (int e = tid * 4; e < TABN - 1; e += 1024) {
        float4 qv = *(const float4*)(atab + e);
        float nx = atab[e + 4];
        float4 lo = make_float4(qv.x, qv.y - qv.x, qv.y, qv.z - qv.y);
        float4 hi = make_float4(qv.z, qv.w - qv.z, qv.w, nx - qv.w);
        *(float4*)(&tab[e]) = lo;
        *(float4*)(&tab[e + 2]) = hi;
    }
    if (tid == 0)
        tab[TABN - 1] = make_float2(atab[TABN - 1], atab[TABN] - atab[TABN - 1]);
    if (tid < TT)
        t32s[tid] = bf ? bf2f(((const u16*)traw)[tid]) : ((const float*)traw)[tid];

    float d   = bf ? bf2f(((const u16*)Draw)[0])  : ((const float*)Draw)[0];
    float bc0 = bf ? bf2f(((const u16*)BCraw)[0]) : ((const float*)BCraw)[0];
    float bc1 = bf ? bf2f(((const u16*)BCraw)[1]) : ((const float*)BCraw)[1];

    int lane = tid & 63;
    int wid = blockIdx.x * 4 + (tid >> 6);
    int gb = wid * OUTW - HALO + lane * VC;   // this lane's first cell (global)
    int i0 = lane * VC;                        // window-local
    bool first = (s0 == 0);
    // only blocks 0 and 255 contain out-of-domain (ghost) lanes
    bool edgeblk = (blockIdx.x == 0) || (blockIdx.x == gridDim.x - 1);

    float v[VC], ub[VC], gfix[VC];
    bool gok[VC], own[VC];
#pragma unroll
    for (int j = 0; j < VC; ++j) {
        int g = gb + j;
        int i = i0 + j;
        gok[j] = (g >= 0) && (g < NXC);
        own[j] = (i >= HALO) && (i < HALO + OUTW);
        float x;
        if (first) {
            if (bf) {
                u16 raw = gok[j] ? ((const u16*)uin)[g] : (u16)0;
                x = bf2f(raw);
                if (own[j]) ((u16*)outbase)[g] = raw;       // row 0 passthrough
            } else {
                float raw = gok[j] ? ((const float*)uin)[g] : 0.f;
                x = raw;
                if (own[j]) ((float*)outbase)[g] = raw;
            }
        } else {
            x = gok[j] ? ((const float*)uin)[g] : 0.f;
        }
        if (!gok[j]) x = (g < 0) ? bc0 : bc1;   // frozen ghost BC cells
        gfix[j] = x;                             // repair value (== x if gok)
        v[j] = x;
        ub[j] = x;
    }
    __syncthreads();  // table + t32s ready; no barriers after this

    // pending table lookup per cell: frac + (value, slope), from current v[j]
    float pf[VC];
    float2 pt[VC];
#pragma unroll
    for (int j = 0; j < VC; ++j) {
        float f = fmaf(v[j], TABINV, (-TABLO) * TABINV);
        f = fminf(fmaxf(f, 0.0f), (float)(TABN - 1));
        int e0 = (int)f;
        pf[j] = FRACTF(f);
        pt[j] = tab[e0];                     // ds_read_b64, in flight
    }

    for (int st = 0; st < nsteps; ++st) {
        int step = s0 + st;
        float dt = t32s[step + 1] - t32s[step];
        float dt2 = 0.5f * dt, dt6 = dt * (1.0f / 6.0f);
        float kacc[VC], kv[VC];
#pragma unroll
        for (int j = 0; j < VC; ++j) kacc[j] = 0.f;
#pragma unroll
        for (int s = 0; s < 4; ++s) {
            float cnext = (s < 2) ? dt2 : dt;
            float wgt = (s == 1 || s == 2) ? 2.f : 1.f;
            float vup = dpp_up1(v[VC - 1]);    // left nbr of cell j=0
            float vdn = dpp_dn1(v[0]);         // right nbr of j=VC-1
#pragma unroll
            for (int j = 0; j < VC; ++j) {
                float vc = v[j];
                float vl = (j == 0) ? vup : v[j - 1];
                float vr = (j == VC - 1) ? vdn : v[j + 1];
                float a = fmaf(pf[j], pt[j].y, pt[j].x);   // consume lookup
                float ap = fmaxf(a, 0.f);
                float am = fminf(a, 0.f);
                kv[j] = (vl - vc) * (d + ap) + (vr - vc) * (d - am);
            }
#pragma unroll
            for (int j = 0; j < VC; ++j) {
                kacc[j] += wgt * kv[j];
                float nv = (s < 3) ? fmaf(cnext, kv[j], ub[j])
                                   : fmaf(dt6, kacc[j], ub[j]);
                v[j] = nv;                      // unconditional (no cndmask)
                if (s == 3) ub[j] = nv;
                // issue next stage's lookup from the just-updated v[j]
                float f = fmaf(v[j], TABINV, (-TABLO) * TABINV);
                f = fminf(fmaxf(f, 0.0f), (float)(TABN - 1));
                int e0 = (int)f;
                pf[j] = FRACTF(f);
                pt[j] = tab[e0];
            }
            if (edgeblk) {   // block-uniform: skipped by 254/256 blocks
#pragma unroll
                for (int j = 0; j < VC; ++j)
                    if (!gok[j]) { v[j] = gfix[j]; ub[j] = gfix[j]; }
                // ghost pending-lookup garbage only feeds the ghost cell's
                // own flux, which is discarded by this repair each stage.
            }
        }
        if (bf) {
            u16* orow = (u16*)outbase + (size_t)(step + 1) * NXC;
#pragma unroll
            for (int j = 0; j < VC; ++j)
                if (own[j]) orow[gb + j] = f2bf(ub[j]);
        } else {
            float* orow = (float*)outbase + (size_t)(step + 1) * NXC;
#pragma unroll
            for (int j = 0; j < VC; ++j)
                if (own[j]) orow[gb + j] = ub[j];
        }
    }
    // chunk-final state for owned cells (skipped for the last chunk)
    if (uout != nullptr) {
#pragma unroll
        for (int j = 0; j < VC; ++j)
            if (own[j]) uout[gb + j] = ub[j];
    }
}

extern "C" void kernel_launch(void* const* d_in, const int* in_sizes, int n_in,
                              void* d_out, int out_size, void* d_ws,
                              size_t ws_size, hipStream_t stream) {
    const void* t  = d_in[0];
    const void* u0 = d_in[1];
    const void* W1 = d_in[2];
    const void* W2 = d_in[3];
    const void* W3 = d_in[4];
    const void* Dp = d_in[5];
    const void* BC = d_in[6];

    float* atab = (float*)d_ws;                    // TABNP+2 floats
    u16* w2frag = (u16*)(atab + TABNP + 2);        // offset 24592 B, 16B-aligned
    float* uB = (float*)(w2frag + 16384);          // NXC f32 mid-state

    w2swz_kernel<<<64, 256, 0, stream>>>(t, W2, w2frag);
    tabbuild_kernel<<<(TABNP + 63) / 64, 256, 0, stream>>>(t, W1, W3, w2frag, atab);

    chunk_kernel<<<NXC / (OUTW * 4), 256, 0, stream>>>(t, u0, uB, Dp, BC, atab,
                                                       d_out, 0, 16);
    chunk_kernel<<<NXC / (OUTW * 4), 256, 0, stream>>>(t, uB, nullptr, Dp, BC, atab,
                                                       d_out, 16, 15);
}